// Round 10
// baseline (345.611 us; speedup 1.0000x reference)
//
#include <hip/hip_runtime.h>
#include <stdint.h>

#define Mdim 8192
#define Ndim 4096
#define Kdim 4096

#define BM 256
#define BN 256
#define BK 64
#define NT2 (Kdim / BK)   // 64 K-tiles

typedef float f32x4 __attribute__((ext_vector_type(4)));
typedef __bf16 bf16x8 __attribute__((ext_vector_type(8)));
typedef unsigned short ushort_t;

#define FMAXC 3.3858093490333422e+38f  // FLT_MAX * (1 - 0.005)

__device__ __forceinline__ ushort_t f2bf(float f) {
    unsigned u = __float_as_uint(f);
    u += 0x7fffu + ((u >> 16) & 1u);   // round-to-nearest-even
    return (ushort_t)(u >> 16);
}

__device__ __forceinline__ void gload_lds16(const void* g, void* l) {
    __builtin_amdgcn_global_load_lds(
        (const __attribute__((address_space(1))) uint32_t*)g,
        (__attribute__((address_space(3))) uint32_t*)(uint32_t)(uintptr_t)l,
        16, 0, 0);
}

#define SGB(mask, n) __builtin_amdgcn_sched_group_barrier(mask, n, 0)

// ---------------------------------------------------------------------------
// Kernel 1: dequant + CSR outliers -> bf16 weight row. Unchanged (passed).
// ---------------------------------------------------------------------------
__global__ __launch_bounds__(128) void dequant_kernel(
        const int* __restrict__ qw, const float* __restrict__ lut,
        const int* __restrict__ rows, const int* __restrict__ cols,
        const float* __restrict__ vals, ushort_t* __restrict__ w16) {
    __shared__ float wrow[128 * 33];
    __shared__ float slut[16];
    const int o = blockIdx.x;
    const int t = threadIdx.x;

    if (t < 16) slut[t] = lut[o * 16 + t];
    __syncthreads();

    const int q0 = qw[0 * Ndim * 128 + o * 128 + t];
    const int q1 = qw[1 * Ndim * 128 + o * 128 + t];
    const int q2 = qw[2 * Ndim * 128 + o * 128 + t];
    const int q3 = qw[3 * Ndim * 128 + o * 128 + t];
    float* dst = &wrow[t * 33];
#pragma unroll
    for (int j = 0; j < 32; ++j) {
        int idx = (((q0 >> j) & 1) << 3) | (((q1 >> j) & 1) << 2) |
                  (((q2 >> j) & 1) << 1) | ((q3 >> j) & 1);
        dst[j] = slut[idx];
    }
    __syncthreads();

    const int beg = rows[o], end = rows[o + 1];
    for (int k = beg + t; k < end; k += 128) {
        int c = cols[k];
        atomicAdd(&wrow[c + (c >> 5)], vals[k]);
    }
    __syncthreads();

    __align__(16) ushort_t tmp[32];
#pragma unroll
    for (int j = 0; j < 32; ++j) tmp[j] = f2bf(dst[j]);
    uint4* dstg = (uint4*)(w16 + (size_t)o * Kdim + t * 32);
    const uint4* srcg = (const uint4*)tmp;
#pragma unroll
    for (int j = 0; j < 4; ++j) dstg[j] = srcg[j];
}

// ---------------------------------------------------------------------------
// Kernel 2: x f32 -> bf16. Unchanged (HBM-bound, ~30 us).
// ---------------------------------------------------------------------------
__global__ __launch_bounds__(256) void convx_kernel(
        const float* __restrict__ x, ushort_t* __restrict__ y) {
    size_t i = ((size_t)blockIdx.x * 256 + threadIdx.x) * 8;
    float4 a = *(const float4*)(x + i);
    float4 b = *(const float4*)(x + i + 4);
    __align__(16) ushort_t r[8] = {f2bf(a.x), f2bf(a.y), f2bf(a.z), f2bf(a.w),
                                   f2bf(b.x), f2bf(b.y), f2bf(b.z), f2bf(b.w)};
    *(uint4*)(y + i) = *(const uint4*)r;
}

// ---------------------------------------------------------------------------
// Kernel 3: bf16 GEMM, 256x256, BK=64. AITER-flatmm-style operand split:
//   A: LDS double-buffer (2 x 32 KB), zero-conflict swizzle, gload_lds.
//   B: streamed GLOBAL->REGISTER per wave (global_load_dwordx4, 16 rows x
//      64 B per instr), register-double-buffered one k-step ahead; its
//      dependencies ride the compiler's per-wave counted vmcnt -> B is off
//      the LDS port AND off the barrier entirely.
// Per CU per tile: MFMA 2483 cyc vs LDS port ~1792 -> matrix-pipe-bound.
// A-reads woven {1 DS : 4 MFMA} (A[m] feeds 4 MFMAs, 2-read lookahead).
// One raw s_barrier per tile; manual wait = vmcnt(4) (A-stage residency,
// leaves next-tile B k0 loads in flight). Never vmcnt(0) in the loop.
// Correctness: stage(t+1) writes buf (t-1)&1 whose ds_reads were consumed
// by MFMAs before the end-of-(t-1) barrier; A(t+1) residency forced by the
// (compiler-subsumed + manual) vmcnt(4) before the end-of-t barrier.
// ---------------------------------------------------------------------------
__global__ __launch_bounds__(512, 2) void gemm_kernel(
        const ushort_t* __restrict__ A, const ushort_t* __restrict__ Bw,
        const float* __restrict__ bias, float* __restrict__ C) {
    __shared__ __align__(16) char lds[65536];   // A dbuf only

    // XCD swizzle, bn-fastest: 32 concurrent blocks/XCD share one A panel.
    const int wgid = blockIdx.x;
    const int swz = (wgid & 7) * 64 + (wgid >> 3);
    const int bn = swz & 15, bm = swz >> 4;
    const int m0 = bm * BM, n0 = bn * BN;

    const int tid = threadIdx.x;
    const int lane = tid & 63, wid = tid >> 6;
    const int wr = wid >> 2, wc = wid & 3;       // 2M x 4N wave grid
    const int fr = lane & 15, kg = lane >> 4;

    // ---- A staging geometry (inverse-swizzled source, linear LDS dest)
    const int srow = tid >> 3;
    const int scol = (((tid & 7) ^ (srow & 7)) * 8);
    const ushort_t* gA = A + (size_t)(m0 + srow) * Kdim + scol;

    // ---- A ds_read swizzled offsets per k-step (row stride 128 B)
    const int off0 = fr * 128 + (((kg) ^ (fr & 7)) << 4);
    const int off1 = fr * 128 + (((4 | kg) ^ (fr & 7)) << 4);

    // ---- B per-lane fragment pointers (row = n0+wc*64+nf*16+fr, col kg*8)
    const ushort_t* pB0 = Bw + (size_t)(n0 + wc * 64 + 0 * 16 + fr) * Kdim + kg * 8;
    const ushort_t* pB1 = pB0 + (size_t)16 * Kdim;
    const ushort_t* pB2 = pB0 + (size_t)32 * Kdim;
    const ushort_t* pB3 = pB0 + (size_t)48 * Kdim;

    f32x4 acc[8][4];
#pragma unroll
    for (int i = 0; i < 8; ++i)
#pragma unroll
        for (int j = 0; j < 4; ++j) acc[i][j] = (f32x4){0.f, 0.f, 0.f, 0.f};

    const ushort_t* pAs = gA;                    // next A K-tile to stage
    auto stageA = [&](int buf) {
        char* d = lds + buf * 32768 + tid * 16;
#pragma unroll
        for (int j = 0; j < 4; ++j)
            gload_lds16(pAs + (size_t)j * 64 * Kdim, d + j * 8192);
    };

    // one tile: consume Bc (k0, loaded last tile); load Bt (k1) and Bn
    // (next tile's k0); stage A(t+1); 64 MFMA; vmcnt(4); barrier.
    auto halfTile = [&](int bufi, int bufn, bf16x8 (&Bc)[4], bf16x8 (&Bn)[4]) {
        const char* Ab = lds + bufi * 32768;
        stageA(bufn);                                  // tile t+1 -> other buf
        pAs += BK;

        bf16x8 FA0[8];
#pragma unroll
        for (int m = 0; m < 8; ++m)
            FA0[m] = *(const bf16x8*)(Ab + wr * 16384 + m * 2048 + off0);
        bf16x8 Bt[4];
        Bt[0] = *(const bf16x8*)(pB0 + 32); Bt[1] = *(const bf16x8*)(pB1 + 32);
        Bt[2] = *(const bf16x8*)(pB2 + 32); Bt[3] = *(const bf16x8*)(pB3 + 32);

        __builtin_amdgcn_s_setprio(1);
#pragma unroll
        for (int m = 0; m < 8; ++m)
#pragma unroll
            for (int n = 0; n < 4; ++n)
                acc[m][n] = __builtin_amdgcn_mfma_f32_16x16x32_bf16(
                    FA0[m], Bc[n], acc[m][n], 0, 0, 0);

        bf16x8 FA1[8];
#pragma unroll
        for (int m = 0; m < 8; ++m)
            FA1[m] = *(const bf16x8*)(Ab + wr * 16384 + m * 2048 + off1);
        Bn[0] = *(const bf16x8*)(pB0 + 64); Bn[1] = *(const bf16x8*)(pB1 + 64);
        Bn[2] = *(const bf16x8*)(pB2 + 64); Bn[3] = *(const bf16x8*)(pB3 + 64);

#pragma unroll
        for (int m = 0; m < 8; ++m)
#pragma unroll
            for (int n = 0; n < 4; ++n)
                acc[m][n] = __builtin_amdgcn_mfma_f32_16x16x32_bf16(
                    FA1[m], Bt[n], acc[m][n], 0, 0, 0);
        __builtin_amdgcn_s_setprio(0);
        pB0 += BK; pB1 += BK; pB2 += BK; pB3 += BK;

        // emission: {stage 4}{A0 2}{Bk1 4}{4 MFMA,1 DS}x6{MFMA 8}
        //           {A1 2}{Bnext 4}{4 MFMA,1 DS}x6{MFMA 8}
        SGB(0x30, 4);
        SGB(0x100, 2); SGB(0x30, 4);
#pragma unroll
        for (int i = 0; i < 6; ++i) { SGB(0x8, 4); SGB(0x100, 1); }
        SGB(0x8, 8);
        SGB(0x100, 2); SGB(0x30, 4);
#pragma unroll
        for (int i = 0; i < 6; ++i) { SGB(0x8, 4); SGB(0x100, 1); }
        SGB(0x8, 8);

        asm volatile("s_waitcnt vmcnt(4)");    // A-stage landed; Bn stays out
        __builtin_amdgcn_sched_barrier(0);
        __builtin_amdgcn_s_barrier();
    };

    // ---- prologue: stage A(0); load B k0(0); wait A(0); barrier
    bf16x8 BA[4], BB[4];
    stageA(0);
    pAs += BK;
    BA[0] = *(const bf16x8*)(pB0); BA[1] = *(const bf16x8*)(pB1);
    BA[2] = *(const bf16x8*)(pB2); BA[3] = *(const bf16x8*)(pB3);
    asm volatile("s_waitcnt vmcnt(4)");
    __builtin_amdgcn_sched_barrier(0);
    __builtin_amdgcn_s_barrier();

    // ===== main loop: tiles 0..61 =====
#pragma unroll 1
    for (int t = 0; t < NT2 - 2; t += 2) {
        halfTile(0, 1, BA, BB);
        halfTile(1, 0, BB, BA);
    }
    // tile 62 (even, buf 0): stages A(63), loads BB = k0(63)
    halfTile(0, 1, BA, BB);

    // ===== tail: tile 63 (buf 1, no stage, no next-B, no barrier) =====
    {
        const char* Ab = lds + 32768;
        bf16x8 FA0[8], FA1[8], Bt[4];
#pragma unroll
        for (int m = 0; m < 8; ++m)
            FA0[m] = *(const bf16x8*)(Ab + wr * 16384 + m * 2048 + off0);
        Bt[0] = *(const bf16x8*)(pB0 + 32); Bt[1] = *(const bf16x8*)(pB1 + 32);
        Bt[2] = *(const bf16x8*)(pB2 + 32); Bt[3] = *(const bf16x8*)(pB3 + 32);
#pragma unroll
        for (int m = 0; m < 8; ++m)
#pragma unroll
            for (int n = 0; n < 4; ++n)
                acc[m][n] = __builtin_amdgcn_mfma_f32_16x16x32_bf16(
                    FA0[m], BB[n], acc[m][n], 0, 0, 0);
#pragma unroll
        for (int m = 0; m < 8; ++m)
            FA1[m] = *(const bf16x8*)(Ab + wr * 16384 + m * 2048 + off1);
#pragma unroll
        for (int m = 0; m < 8; ++m)
#pragma unroll
            for (int n = 0; n < 4; ++n)
                acc[m][n] = __builtin_amdgcn_mfma_f32_16x16x32_bf16(
                    FA1[m], Bt[n], acc[m][n], 0, 0, 0);
    }

    // ---- epilogue: C/D layout col = lane&15, row = (lane>>4)*4 + reg
    const int rg = lane >> 4;
#pragma unroll
    for (int nf = 0; nf < 4; ++nf) {
        const int col = n0 + wc * 64 + nf * 16 + fr;
        const float bv = bias[col];
#pragma unroll
        for (int mf = 0; mf < 8; ++mf) {
            const int row = m0 + wr * 128 + mf * 16 + rg * 4;
            float* outp = C + (size_t)row * Ndim + col;
#pragma unroll
            for (int j = 0; j < 4; ++j) {
                float v = acc[mf][nf][j] + bv;
                v = fminf(fmaxf(v, -FMAXC), FMAXC);
                outp[(size_t)j * Ndim] = v;
            }
        }
    }
}

extern "C" void kernel_launch(void* const* d_in, const int* in_sizes, int n_in,
                              void* d_out, int out_size, void* d_ws, size_t ws_size,
                              hipStream_t stream) {
    const float* x    = (const float*)d_in[0];
    const int*   qw   = (const int*)d_in[1];
    const float* lut  = (const float*)d_in[2];
    const int*   rows = (const int*)d_in[3];
    const int*   cols = (const int*)d_in[4];
    const float* vals = (const float*)d_in[5];
    const float* bias = (const float*)d_in[6];
    float* out = (float*)d_out;

    ushort_t* x16 = (ushort_t*)d_ws;                       // 64 MiB
    ushort_t* w16 = x16 + (size_t)Mdim * Kdim;             // 32 MiB

    hipLaunchKernelGGL(dequant_kernel, dim3(Ndim), dim3(128), 0, stream,
                       qw, lut, rows, cols, vals, w16);
    hipLaunchKernelGGL(convx_kernel, dim3((Mdim * Kdim) / (256 * 8)), dim3(256), 0, stream,
                       x, x16);
    hipLaunchKernelGGL(gemm_kernel, dim3((Mdim / BM) * (Ndim / BN)), dim3(512), 0, stream,
                       x16, w16, bias, out);
}

// Round 11
// 302.922 us; speedup vs baseline: 1.1409x; 1.1409x over previous
//
#include <hip/hip_runtime.h>
#include <stdint.h>

#define Mdim 8192
#define Ndim 4096
#define Kdim 4096

#define BM 256
#define BN 256
#define BK 32
#define NT (Kdim / BK)   // 128 K-tiles

typedef float f32x4 __attribute__((ext_vector_type(4)));
typedef __bf16 bf16x8 __attribute__((ext_vector_type(8)));
typedef unsigned short ushort_t;

#define FMAXC 3.3858093490333422e+38f  // FLT_MAX * (1 - 0.005)

__device__ __forceinline__ ushort_t f2bf(float f) {
    unsigned u = __float_as_uint(f);
    u += 0x7fffu + ((u >> 16) & 1u);   // round-to-nearest-even
    return (ushort_t)(u >> 16);
}

__device__ __forceinline__ void gload_lds16(const void* g, void* l) {
    __builtin_amdgcn_global_load_lds(
        (const __attribute__((address_space(1))) uint32_t*)g,
        (__attribute__((address_space(3))) uint32_t*)(uint32_t)(uintptr_t)l,
        16, 0, 0);
}

// ---------------------------------------------------------------------------
// Kernel 1: dequant + CSR outliers -> bf16 weight row. Unchanged (passed).
// ---------------------------------------------------------------------------
__global__ __launch_bounds__(128) void dequant_kernel(
        const int* __restrict__ qw, const float* __restrict__ lut,
        const int* __restrict__ rows, const int* __restrict__ cols,
        const float* __restrict__ vals, ushort_t* __restrict__ w16) {
    __shared__ float wrow[128 * 33];
    __shared__ float slut[16];
    const int o = blockIdx.x;
    const int t = threadIdx.x;

    if (t < 16) slut[t] = lut[o * 16 + t];
    __syncthreads();

    const int q0 = qw[0 * Ndim * 128 + o * 128 + t];
    const int q1 = qw[1 * Ndim * 128 + o * 128 + t];
    const int q2 = qw[2 * Ndim * 128 + o * 128 + t];
    const int q3 = qw[3 * Ndim * 128 + o * 128 + t];
    float* dst = &wrow[t * 33];
#pragma unroll
    for (int j = 0; j < 32; ++j) {
        int idx = (((q0 >> j) & 1) << 3) | (((q1 >> j) & 1) << 2) |
                  (((q2 >> j) & 1) << 1) | ((q3 >> j) & 1);
        dst[j] = slut[idx];
    }
    __syncthreads();

    const int beg = rows[o], end = rows[o + 1];
    for (int k = beg + t; k < end; k += 128) {
        int c = cols[k];
        atomicAdd(&wrow[c + (c >> 5)], vals[k]);
    }
    __syncthreads();

    __align__(16) ushort_t tmp[32];
#pragma unroll
    for (int j = 0; j < 32; ++j) tmp[j] = f2bf(dst[j]);
    uint4* dstg = (uint4*)(w16 + (size_t)o * Kdim + t * 32);
    const uint4* srcg = (const uint4*)tmp;
#pragma unroll
    for (int j = 0; j < 4; ++j) dstg[j] = srcg[j];
}

// ---------------------------------------------------------------------------
// Kernel 2: x f32 -> bf16. Unchanged (HBM-bound, ~30 us).
// ---------------------------------------------------------------------------
__global__ __launch_bounds__(256) void convx_kernel(
        const float* __restrict__ x, ushort_t* __restrict__ y) {
    size_t i = ((size_t)blockIdx.x * 256 + threadIdx.x) * 8;
    float4 a = *(const float4*)(x + i);
    float4 b = *(const float4*)(x + i + 4);
    __align__(16) ushort_t r[8] = {f2bf(a.x), f2bf(a.y), f2bf(a.z), f2bf(a.w),
                                   f2bf(b.x), f2bf(b.y), f2bf(b.z), f2bf(b.w)};
    *(uint4*)(y + i) = *(const uint4*)r;
}

// ---------------------------------------------------------------------------
// Kernel 3: bf16 GEMM, 256x256, BK=32, ring-4 LDS, m201-style PHASE template:
//   2 phases per K-tile, 16 MFMA each; per phase a SMALL ds_read burst (4 or
//   8 b128) issued ONE PHASE AHEAD of its MFMAs; COUNTED lgkmcnt(4/8) before
//   each MFMA cluster (waits prior-phase reads, leaves this phase's in
//   flight); one counted vmcnt(2) per tile; double barrier per phase;
//   setprio(1) around MFMA clusters (T5, gated on phase structure).
// Phase map (tile t, Ac/An = A-half reg sets, Bc/Bn = B reg sets):
//   P0: read A4-7(t)->An (4 ds, buf t&3); stage A(t+2); vmcnt(2); BAR;
//       lgkm(4); 16 MFMA m0-3 (Ac x Bc); BAR
//   P1: read A0-3(t+1)->Ac + B(t+1)->Bn (8 ds, buf (t+1)&3); stage B(t+2);
//       BAR; lgkm(8); 16 MFMA m4-7 (An x Bc); BAR
// Ring-4, stage distance 2:
//   WAR: stage(t+2) overwrites buf[(t-2)&3], fully consumed by end of tile
//        t-2 (>=4 barriers earlier).
//   RAW: vmcnt(2) at P0(t) leaves only A(t+2)'s 2 loads outstanding ->
//        A(t+1),B(t+1) LDS-resident before P1(t)'s reads of buf (t+1)&3;
//        barrier globalizes across waves.
//   lgkm: DS ops complete in-order per wave -> lgkmcnt(N) with N = newest
//        burst size guarantees all older reads landed.
// ---------------------------------------------------------------------------
__global__ __launch_bounds__(512, 2) void gemm_kernel(
        const ushort_t* __restrict__ A, const ushort_t* __restrict__ Bw,
        const float* __restrict__ bias, float* __restrict__ C) {
    __shared__ __align__(16) char lds[131072];

    // XCD swizzle, bn-fastest: 32 concurrent blocks per XCD share one A panel
    // (L2-resident), stream B via L3. nwg=512 (%8==0).
    const int wgid = blockIdx.x;
    const int swz = (wgid & 7) * 64 + (wgid >> 3);
    const int bn = swz & 15, bm = swz >> 4;
    const int m0 = bm * BM, n0 = bn * BN;

    const int tid = threadIdx.x;
    const int lane = tid & 63, wid = tid >> 6;
    const int wr = wid >> 2, wc = wid & 3;       // 2M x 4N wave grid
    const int fr = lane & 15, kg = lane >> 4;

    // ---- staging geometry (inverse-swizzled global source, linear LDS dest)
    const int sline = tid >> 3;
    const int slot = (tid & 7) ^ (sline & 7);
    const int srow0 = (sline << 1) + (slot >> 2);          // + j*128
    const int skel = (slot & 3) * 8;                       // k elements
    const ushort_t* gA = A + (size_t)(m0 + srow0) * Kdim + skel;
    const ushort_t* gB = Bw + (size_t)(n0 + srow0) * Kdim + skel;

    // ---- ds_read lane offset (row = base + fr, kslot = kg)
    const int offL = (fr >> 1) * 128 + (((((fr & 1) << 2) | kg) ^ (fr >> 1)) << 4);

    f32x4 acc[8][4];
#pragma unroll
    for (int i = 0; i < 8; ++i)
#pragma unroll
        for (int j = 0; j < 4; ++j) acc[i][j] = (f32x4){0.f, 0.f, 0.f, 0.f};

    // running stage pointers: pA/pB point at next K-tile to stage
    const ushort_t* pA = gA;
    const ushort_t* pB = gB;

    auto stageA = [&](int bufd) {
        char* d = lds + bufd * 16384 + tid * 16;
        gload_lds16(pA, d);
        gload_lds16(pA + (size_t)128 * Kdim, d + 8192);
        pA += BK;
    };
    auto stageB = [&](int bufd) {
        char* d = lds + 65536 + bufd * 16384 + tid * 16;
        gload_lds16(pB, d);
        gload_lds16(pB + (size_t)128 * Kdim, d + 8192);
        pB += BK;
    };
    auto readAlo = [&](bf16x8 (&FA)[4], int buf) {          // A m0-3
#pragma unroll
        for (int m = 0; m < 4; ++m)
            FA[m] = *(const bf16x8*)(lds + buf * 16384 + wr * 8192 + m * 1024 + offL);
    };
    auto readAhi = [&](bf16x8 (&FA)[4], int buf) {          // A m4-7
#pragma unroll
        for (int m = 0; m < 4; ++m)
            FA[m] = *(const bf16x8*)(lds + buf * 16384 + wr * 8192 + (m + 4) * 1024 + offL);
    };
    auto readB = [&](bf16x8 (&FB)[4], int buf) {
#pragma unroll
        for (int n = 0; n < 4; ++n)
            FB[n] = *(const bf16x8*)(lds + 65536 + buf * 16384 + wc * 4096 + n * 1024 + offL);
    };
    auto mfmaHalf = [&](int mb, bf16x8 (&FA)[4], bf16x8 (&FB)[4]) {
        __builtin_amdgcn_s_setprio(1);
#pragma unroll
        for (int m = 0; m < 4; ++m)
#pragma unroll
            for (int n = 0; n < 4; ++n)
                acc[mb + m][n] = __builtin_amdgcn_mfma_f32_16x16x32_bf16(
                    FA[m], FB[n], acc[mb + m][n], 0, 0, 0);
        __builtin_amdgcn_s_setprio(0);
    };

    bf16x8 Ac[4], An[4], BA[4], BB[4];

    // tile body: Bc = B(t) regs, Bn receives B(t+1)
    auto tileMain = [&](int t, bf16x8 (&Bc)[4], bf16x8 (&Bn)[4]) {
        const int bufR = t & 3, bufR1 = (t + 1) & 3, bufS = (t + 2) & 3;
        // ----- P0 -----
        readAhi(An, bufR);
        stageA(bufS);
        asm volatile("s_waitcnt vmcnt(2)");      // A(t+1),B(t+1) resident
        __builtin_amdgcn_sched_barrier(0);
        __builtin_amdgcn_s_barrier();
        asm volatile("s_waitcnt lgkmcnt(4)");    // prior-phase reads landed
        __builtin_amdgcn_sched_barrier(0);
        mfmaHalf(0, Ac, Bc);
        __builtin_amdgcn_s_barrier();
        // ----- P1 -----
        readAlo(Ac, bufR1);
        readB(Bn, bufR1);
        stageB(bufS);
        __builtin_amdgcn_sched_barrier(0);
        __builtin_amdgcn_s_barrier();
        asm volatile("s_waitcnt lgkmcnt(8)");
        __builtin_amdgcn_sched_barrier(0);
        mfmaHalf(4, An, Bc);
        __builtin_amdgcn_s_barrier();
    };

    // ---- prologue: stage tiles 0,1; read tile-0 frags
    stageA(0); stageB(0);
    stageA(1); stageB(1);
    asm volatile("s_waitcnt vmcnt(4)");          // tile 0 resident
    __builtin_amdgcn_sched_barrier(0);
    __builtin_amdgcn_s_barrier();
    readAlo(Ac, 0);
    readB(BA, 0);

    // ===== main loop: tiles 0..NT-3 (each stages t+2) =====
#pragma unroll 1
    for (int t = 0; t < NT - 2; t += 2) {
        tileMain(t, BA, BB);
        tileMain(t + 1, BB, BA);
    }

    // ===== peel tile NT-2 (=126): no staging; drain vmcnt for tile 127 =====
    {
        const int bufR = (NT - 2) & 3, bufR1 = (NT - 1) & 3;
        readAhi(An, bufR);
        asm volatile("s_waitcnt vmcnt(0)");      // tile 127 resident
        __builtin_amdgcn_sched_barrier(0);
        __builtin_amdgcn_s_barrier();
        asm volatile("s_waitcnt lgkmcnt(4)");
        __builtin_amdgcn_sched_barrier(0);
        mfmaHalf(0, Ac, BA);
        __builtin_amdgcn_s_barrier();
        readAlo(Ac, bufR1);
        readB(BB, bufR1);
        __builtin_amdgcn_sched_barrier(0);
        __builtin_amdgcn_s_barrier();
        asm volatile("s_waitcnt lgkmcnt(8)");
        __builtin_amdgcn_sched_barrier(0);
        mfmaHalf(4, An, BA);
        __builtin_amdgcn_s_barrier();
    }
    // ===== peel tile NT-1 (=127): last tile, no staging/barriers after =====
    {
        const int bufR = (NT - 1) & 3;
        readAhi(An, bufR);
        asm volatile("s_waitcnt lgkmcnt(4)");
        __builtin_amdgcn_sched_barrier(0);
        mfmaHalf(0, Ac, BB);
        asm volatile("s_waitcnt lgkmcnt(0)");
        __builtin_amdgcn_sched_barrier(0);
        mfmaHalf(4, An, BB);
    }

    // ---- epilogue: C/D layout col = lane&15, row = (lane>>4)*4 + reg
    const int rg = lane >> 4;
#pragma unroll
    for (int nf = 0; nf < 4; ++nf) {
        const int col = n0 + wc * 64 + nf * 16 + fr;
        const float bv = bias[col];
#pragma unroll
        for (int mf = 0; mf < 8; ++mf) {
            const int row = m0 + wr * 128 + mf * 16 + rg * 4;
            float* outp = C + (size_t)row * Ndim + col;
#pragma unroll
            for (int j = 0; j < 4; ++j) {
                float v = acc[mf][nf][j] + bv;
                v = fminf(fmaxf(v, -FMAXC), FMAXC);
                outp[(size_t)j * Ndim] = v;
            }
        }
    }
}

extern "C" void kernel_launch(void* const* d_in, const int* in_sizes, int n_in,
                              void* d_out, int out_size, void* d_ws, size_t ws_size,
                              hipStream_t stream) {
    const float* x    = (const float*)d_in[0];
    const int*   qw   = (const int*)d_in[1];
    const float* lut  = (const float*)d_in[2];
    const int*   rows = (const int*)d_in[3];
    const int*   cols = (const int*)d_in[4];
    const float* vals = (const float*)d_in[5];
    const float* bias = (const float*)d_in[6];
    float* out = (float*)d_out;

    ushort_t* x16 = (ushort_t*)d_ws;                       // 64 MiB
    ushort_t* w16 = x16 + (size_t)Mdim * Kdim;             // 32 MiB

    hipLaunchKernelGGL(dequant_kernel, dim3(Ndim), dim3(128), 0, stream,
                       qw, lut, rows, cols, vals, w16);
    hipLaunchKernelGGL(convx_kernel, dim3((Mdim * Kdim) / (256 * 8)), dim3(256), 0, stream,
                       x, x16);
    hipLaunchKernelGGL(gemm_kernel, dim3((Mdim / BM) * (Ndim / BN)), dim3(512), 0, stream,
                       x16, w16, bias, out);
}